// Round 9
// baseline (446.331 us; speedup 1.0000x reference)
//
#include <hip/hip_runtime.h>
#include <hip/hip_bf16.h>

#define TTOT 65536  // 16 * 4096 rows

using f32x4 = __attribute__((ext_vector_type(4))) float;
using s16x8 = __attribute__((ext_vector_type(8))) short;
typedef unsigned short u16;
using u16x8 = __attribute__((ext_vector_type(8))) u16;

typedef __attribute__((address_space(3))) void lds_void;
typedef __attribute__((address_space(1))) void g_void;

__device__ __forceinline__ float bf2f(u16 u) {
    union { unsigned int ui; float f; } v; v.ui = ((unsigned int)u) << 16; return v.f;
}

__device__ __forceinline__ u16 f2bf(float f) {
    return __bfloat16_as_ushort(__float2bfloat16(f));
}

// ---------------- weight transpose + bf16 convert: wt[n*K+k] = w[k*N+n] ----
__global__ void wconv_t(const float* __restrict__ w, __hip_bfloat16* __restrict__ wt,
                        int K, int N) {
    int idx = blockIdx.x * 256 + threadIdx.x;
    if (idx >= K * N) return;
    int n = idx / K, k = idx - n * K;
    wt[idx] = __float2bfloat16(w[(long)k * N + n]);
}

// ---------------- ada = silu(c) @ ada_w + ada_b   (16 x 1536) --------------
__global__ __launch_bounds__(256) void ada_kernel(const float* __restrict__ c,
                                                  const float* __restrict__ ada_w,
                                                  const float* __restrict__ ada_b,
                                                  float* __restrict__ ada) {
    __shared__ float sc[16 * 256];
    int tid = threadIdx.x;
    for (int i = tid; i < 16 * 256; i += 256) {
        float v = c[i];
        sc[i] = v / (1.0f + expf(-v));
    }
    __syncthreads();
    int j = blockIdx.x * 256 + tid;   // grid = 6 -> j in [0,1536)
    float b = ada_b[j];
    for (int n = 0; n < 16; n++) {
        float acc = b;
        for (int k = 0; k < 256; k++)
            acc += sc[n * 256 + k] * ada_w[(long)k * 1536 + j];
        ada[n * 1536 + j] = acc;
    }
}

// ---------------- fused LayerNorm + modulate -> bf16 -----------------------
__global__ __launch_bounds__(256) void ln_mod(const float* __restrict__ x,
                                              const float* __restrict__ ada,
                                              int off_sh, int off_sc,
                                              __hip_bfloat16* __restrict__ out) {
    int row = blockIdx.x * 4 + (threadIdx.x >> 6);
    int lane = threadIdx.x & 63;
    const float4 v = *(const float4*)&x[(long)row * 256 + lane * 4];
    float s = v.x + v.y + v.z + v.w;
    float s2 = v.x * v.x + v.y * v.y + v.z * v.z + v.w * v.w;
#pragma unroll
    for (int o = 32; o > 0; o >>= 1) {
        s += __shfl_xor(s, o, 64);
        s2 += __shfl_xor(s2, o, 64);
    }
    float mu = s * (1.0f / 256.0f);
    float var = s2 * (1.0f / 256.0f) - mu * mu;
    float rstd = rsqrtf(var + 1e-6f);
    int nb = row >> 12;
    const float* sh = &ada[nb * 1536 + off_sh];
    const float* scp = &ada[nb * 1536 + off_sc];
    float vv[4] = {v.x, v.y, v.z, v.w};
#pragma unroll
    for (int e = 0; e < 4; e++) {
        int col = lane * 4 + e;
        float val = (vv[e] - mu) * rstd;
        val = val * (1.0f + scp[col]) + sh[col];
        out[(long)row * 256 + col] = __float2bfloat16(val);
    }
}

// ---------------- bf16 MFMA GEMM, M-stream (round-4 core + KM tiles) -------
// 2-phase dbuf pipeline (counted vmcnt), XOR-swizzled LDS, wave-uniform DMA.
// Each block processes KM consecutive 128-row M-tiles; the load pipeline
// stays warm across tile boundaries (epilogue runs with next tile's loads
// in flight). K fixed at 256 (NT=4 steps/tile).
// MODE 0: qkv   -> outb = acc + bias                        (bf16)
// MODE 1: proj  -> outf = resid + g_msa * (acc + bias)      (f32, d_out)
template <int MODE, int KM>
__global__ __launch_bounds__(256) void gemm_ms(const __hip_bfloat16* __restrict__ A,
                                               const __hip_bfloat16* __restrict__ Bt,
                                               const float* __restrict__ bias,
                                               const float* __restrict__ resid,
                                               const float* __restrict__ ada,
                                               float* __restrict__ outf,
                                               __hip_bfloat16* __restrict__ outb,
                                               int N) {
    constexpr int K = 256;
    __shared__ u16 As[2][128 * 64];   // linear dest, swizzled content
    __shared__ u16 Bs[2][128 * 64];
    int tid = threadIdx.x;
    int lane = tid & 63;
    int wid = tid >> 6;
    int wr = wid >> 1, wc = wid & 1;
    long base = (long)blockIdx.y * (128 * KM);
    int bcol = blockIdx.x * 128;
    int la = lane & 15, lb = lane >> 4;

    f32x4 acc[4][4] = {};

    const u16* Ag = (const u16*)A;
    const u16* Bg = (const u16*)Bt;

    auto STAGE = [&](long brow, int k0, int buf) {
#pragma unroll
        for (int i = 0; i < 4; i++) {
            int c = (wid * 4 + i) * 64 + lane;   // 16B chunk id, 0..1023
            int row = c >> 3;
            int sc = (c & 7) ^ (row & 7);        // inverse-swizzled source chunk
            __builtin_amdgcn_global_load_lds(
                (const g_void*)(Ag + (brow + row) * K + k0 + sc * 8),
                (lds_void*)&As[buf][(wid * 4 + i) * 512], 16, 0, 0);
            __builtin_amdgcn_global_load_lds(
                (const g_void*)(Bg + (long)(bcol + row) * K + k0 + sc * 8),
                (lds_void*)&Bs[buf][(wid * 4 + i) * 512], 16, 0, 0);
        }
    };

    constexpr int NS = KM * 4;
    STAGE(base, 0, 0);
    for (int j = 0; j < NS; ++j) {
        int cur = j & 1;
        if (j + 1 < NS) {
            int jm = j + 1;
            STAGE(base + (long)(jm >> 2) * 128, (jm & 3) << 6, cur ^ 1);
            asm volatile("s_waitcnt vmcnt(8)" ::: "memory");   // tile j landed
        } else {
            asm volatile("s_waitcnt vmcnt(0)" ::: "memory");
        }
        __builtin_amdgcn_s_barrier();   // tile j visible to all waves
#pragma unroll
        for (int kk8 = 0; kk8 < 8; kk8 += 4) {   // kk = kk8*8 in {0,32}
            s16x8 af[4], bfr[4];
#pragma unroll
            for (int m = 0; m < 4; m++) {
                int R = wr * 64 + m * 16 + la;
                af[m] = *(const s16x8*)&As[cur][R * 64 + (((kk8 + lb) ^ (R & 7)) << 3)];
            }
#pragma unroll
            for (int n2 = 0; n2 < 4; n2++) {
                int R = wc * 64 + n2 * 16 + la;
                bfr[n2] = *(const s16x8*)&Bs[cur][R * 64 + (((kk8 + lb) ^ (R & 7)) << 3)];
            }
#pragma unroll
            for (int m = 0; m < 4; m++)
#pragma unroll
                for (int n2 = 0; n2 < 4; n2++)
                    acc[m][n2] = __builtin_amdgcn_mfma_f32_16x16x32_bf16(
                        af[m], bfr[n2], acc[m][n2], 0, 0, 0);
        }

        if ((j & 3) == 3) {
            // epilogue for M-tile (j>>2); next tile's loads already in flight
            long brow = base + (long)(j >> 2) * 128;
            int nb = (int)(brow >> 12);
#pragma unroll
            for (int m = 0; m < 4; m++) {
#pragma unroll
                for (int n2 = 0; n2 < 4; n2++) {
#pragma unroll
                    for (int r = 0; r < 4; r++) {
                        long row = brow + wr * 64 + m * 16 + lb * 4 + r;
                        int col = bcol + wc * 64 + n2 * 16 + la;
                        float v = acc[m][n2][r] + bias[col];
                        long oidx = row * N + col;
                        if (MODE == 0) {
                            outb[oidx] = __float2bfloat16(v);
                        } else {
                            float g = ada[nb * 1536 + 512 + col];
                            outf[oidx] = resid[oidx] + g * v;
                        }
                        acc[m][n2][r] = 0.0f;
                    }
                }
            }
        }
        __builtin_amdgcn_s_barrier();   // reads done before buffer reuse
    }
}

// ---------------- fused MLP v2: LN+mod -> fc1 -> gelu -> fc2 -> residual ---
// Block = 256 thr / 4 waves, 64-row panel, HID chunks of 128.
// LDS = xa 33.8K + hb 17.4K = 51 KB -> 3 blocks/CU (12 waves, 3/SIMD).
// h1 never touches HBM. B-operands read per-lane from L2.
__global__ __launch_bounds__(256, 3) void mlp_fused(float* __restrict__ outf,
                                                    const __hip_bfloat16* __restrict__ fc1w,
                                                    const float* __restrict__ fc1_b,
                                                    const __hip_bfloat16* __restrict__ fc2w,
                                                    const float* __restrict__ fc2_b,
                                                    const float* __restrict__ ada) {
    __shared__ u16 xa[64 * 264];   // LN+mod rows, bf16, pad 264
    __shared__ u16 hb[64 * 136];   // gelu(h1) 128-col chunk, bf16, pad 136

    int tid = threadIdx.x;
    int lane = tid & 63;
    int w = tid >> 6;              // wave 0..3
    int la = lane & 15, lb = lane >> 4;
    long mrow = (long)blockIdx.x * 64;
    int nb = (int)(mrow >> 12);

    const u16* F1 = (const u16*)fc1w;   // [1024][256]
    const u16* F2 = (const u16*)fc2w;   // [256][1024]

    // ---- Phase 0: LN + modulate (MLP branch) out1 -> xa ----
    const float* sh = &ada[nb * 1536 + 768];
    const float* scp = &ada[nb * 1536 + 1024];
#pragma unroll
    for (int i = 0; i < 16; i++) {
        int row = i * 4 + w;
        const float4 v = *(const float4*)&outf[(mrow + row) * 256 + lane * 4];
        float s = v.x + v.y + v.z + v.w;
        float s2 = v.x * v.x + v.y * v.y + v.z * v.z + v.w * v.w;
#pragma unroll
        for (int o = 32; o > 0; o >>= 1) {
            s += __shfl_xor(s, o, 64);
            s2 += __shfl_xor(s2, o, 64);
        }
        float mu = s * (1.0f / 256.0f);
        float var = s2 * (1.0f / 256.0f) - mu * mu;
        float rstd = rsqrtf(var + 1e-6f);
        float vv[4] = {v.x, v.y, v.z, v.w};
#pragma unroll
        for (int e = 0; e < 4; e++) {
            int col = lane * 4 + e;
            float val = (vv[e] - mu) * rstd;
            val = val * (1.0f + scp[col]) + sh[col];
            xa[row * 264 + col] = f2bf(val);
        }
    }
    __syncthreads();

    f32x4 acc2[4][4] = {};

#pragma unroll 1
    for (int c = 0; c < 8; c++) {
        // ---- GEMM1: acc1 = xa @ fc1_w[:, c*128 + w*32 ...]  (wave: 32 cols)
        f32x4 acc1[4][2] = {};
        const u16* B1 = F1 + (long)(c * 128 + w * 32) * 256;
#pragma unroll
        for (int k0 = 0; k0 < 4; k0++) {
            s16x8 b1r[2][2];
#pragma unroll
            for (int ct = 0; ct < 2; ct++)
#pragma unroll
                for (int kk = 0; kk < 2; kk++)
                    b1r[ct][kk] = *(const s16x8*)&B1[(ct * 16 + la) * 256 +
                                                     k0 * 64 + kk * 32 + lb * 8];
#pragma unroll
            for (int kk = 0; kk < 2; kk++) {
                s16x8 a[4];
#pragma unroll
                for (int rt = 0; rt < 4; rt++)
                    a[rt] = *(const s16x8*)&xa[(rt * 16 + la) * 264 +
                                               k0 * 64 + kk * 32 + lb * 8];
#pragma unroll
                for (int rt = 0; rt < 4; rt++)
#pragma unroll
                    for (int ct = 0; ct < 2; ct++)
                        acc1[rt][ct] = __builtin_amdgcn_mfma_f32_16x16x32_bf16(
                            a[rt], b1r[ct][kk], acc1[rt][ct], 0, 0, 0);
            }
        }
        // ---- gelu + write hb (wave's 32 cols) ----
#pragma unroll
        for (int ct = 0; ct < 2; ct++) {
            float b1v = fc1_b[c * 128 + w * 32 + ct * 16 + la];
#pragma unroll
            for (int rt = 0; rt < 4; rt++) {
#pragma unroll
                for (int r = 0; r < 4; r++) {
                    float v = acc1[rt][ct][r] + b1v;
                    float u2 = 1.5957691216057308f * (v + 0.044715f * v * v * v);
                    hb[(rt * 16 + lb * 4 + r) * 136 + w * 32 + ct * 16 + la] =
                        f2bf(v / (1.0f + __expf(-u2)));
                }
            }
        }
        __syncthreads();   // hb(c) complete before GEMM2 reads

        // ---- GEMM2: acc2 += hb @ fc2_w[k-chunk c][wave's 64 out-cols] ----
        const u16* B2 = F2 + (long)(w * 64) * 1024 + c * 128;
#pragma unroll
        for (int k0 = 0; k0 < 2; k0++) {
            s16x8 b2r[4][2];
#pragma unroll
            for (int ct = 0; ct < 4; ct++)
#pragma unroll
                for (int kk = 0; kk < 2; kk++)
                    b2r[ct][kk] = *(const s16x8*)&B2[(ct * 16 + la) * 1024 +
                                                     k0 * 64 + kk * 32 + lb * 8];
#pragma unroll
            for (int kk = 0; kk < 2; kk++) {
                s16x8 a[4];
#pragma unroll
                for (int rt = 0; rt < 4; rt++)
                    a[rt] = *(const s16x8*)&hb[(rt * 16 + la) * 136 +
                                               k0 * 64 + kk * 32 + lb * 8];
#pragma unroll
                for (int rt = 0; rt < 4; rt++)
#pragma unroll
                    for (int ct = 0; ct < 4; ct++)
                        acc2[rt][ct] = __builtin_amdgcn_mfma_f32_16x16x32_bf16(
                            a[rt], b2r[ct][kk], acc2[rt][ct], 0, 0, 0);
            }
        }
        __syncthreads();   // GEMM2 reads done before next chunk's hb write
    }

    // ---- epilogue: out = out1 + g_mlp * (acc2 + fc2_b) ----
#pragma unroll
    for (int ct = 0; ct < 4; ct++) {
        int col = w * 64 + ct * 16 + la;
        float g = ada[nb * 1536 + 1280 + col];
        float b2v = fc2_b[col];
#pragma unroll
        for (int rt = 0; rt < 4; rt++) {
#pragma unroll
            for (int r = 0; r < 4; r++) {
                long row = mrow + rt * 16 + lb * 4 + r;
                long oidx = row * 256 + col;
                outf[oidx] = outf[oidx] + g * (acc2[rt][ct][r] + b2v);
            }
        }
    }
}

// ---------------- MFMA window attention ------------------------------------
__global__ __launch_bounds__(256) void win_attn_mfma(const __hip_bfloat16* __restrict__ qkv,
                                                     const float* __restrict__ rpb,
                                                     __hip_bfloat16* __restrict__ out) {
    __shared__ float bias_s[64 * 64];
    __shared__ u16 vt[4][32 * 72];
    __shared__ u16 pl[4][64 * 72];

    int tid = threadIdx.x;
    int bid = blockIdx.x;
    int h = bid & 7;
    int w = tid >> 6;
    int lane = tid & 63;
    int la = lane & 15, lb = lane >> 4;
    int win = (bid >> 3) * 4 + w;
    int n = win >> 6;
    int wh = (win >> 3) & 7;
    int ww = win & 7;
    long base_row = (long)n * 4096 + (long)(wh * 8) * 64 + ww * 8;

    for (int i = tid; i < 4096; i += 256) {
        int t = i >> 6, j = i & 63;
        int idx = ((t >> 3) - (j >> 3) + 7) * 15 + ((t & 7) - (j & 7) + 7);
        bias_s[i] = rpb[idx * 8 + h];
    }

    const u16* qg = (const u16*)qkv;

    s16x8 qf[4], kf[4];
#pragma unroll
    for (int rt = 0; rt < 4; rt++) {
        int t = rt * 16 + la;
        long sr = base_row + (t >> 3) * 64 + (t & 7);
        qf[rt] = *(const s16x8*)(qg + sr * 768 + h * 32 + lb * 8);
        kf[rt] = *(const s16x8*)(qg + sr * 768 + 256 + h * 32 + lb * 8);
    }
#pragma unroll
    for (int g = 0; g < 4; g++) {
        int t = g * 16 + la;
        long sr = base_row + (t >> 3) * 64 + (t & 7);
        u16x8 vv = *(const u16x8*)(qg + sr * 768 + 512 + h * 32 + lb * 8);
#pragma unroll
        for (int e = 0; e < 8; e++) vt[w][(lb * 8 + e) * 72 + t] = vv[e];
    }

    f32x4 sa[4][4];
    f32x4 zero = {};
#pragma unroll
    for (int rt = 0; rt < 4; rt++)
#pragma unroll
        for (int ct = 0; ct < 4; ct++)
            sa[rt][ct] = __builtin_amdgcn_mfma_f32_16x16x32_bf16(qf[rt], kf[ct], zero, 0, 0, 0);

    __syncthreads();

    float rls[4][4];
#pragma unroll
    for (int rt = 0; rt < 4; rt++) {
#pragma unroll
        for (int r = 0; r < 4; r++) {
            int t = rt * 16 + lb * 4 + r;
            float v0 = sa[rt][0][r] * 0.17677669529663687f + bias_s[t * 64 + 0 * 16 + la];
            float v1 = sa[rt][1][r] * 0.17677669529663687f + bias_s[t * 64 + 1 * 16 + la];
            float v2 = sa[rt][2][r] * 0.17677669529663687f + bias_s[t * 64 + 2 * 16 + la];
            float v3 = sa[rt][3][r] * 0.17677669529663687f + bias_s[t * 64 + 3 * 16 + la];
            float mx = fmaxf(fmaxf(v0, v1), fmaxf(v2, v3));
#pragma unroll
            for (int o = 1; o < 16; o <<= 1) mx = fmaxf(mx, __shfl_xor(mx, o, 64));
            float p0 = __expf(v0 - mx), p1 = __expf(v1 - mx);
            float p2 = __expf(v2 - mx), p3 = __expf(v3 - mx);
            float sum = (p0 + p1) + (p2 + p3);
#pragma unroll
            for (int o = 1; o < 16; o <<= 1) sum += __shfl_xor(sum, o, 64);
            sa[rt][0][r] = p0; sa[rt][1][r] = p1; sa[rt][2][r] = p2; sa[rt][3][r] = p3;
            rls[rt][r] = 1.0f / sum;
        }
    }

#pragma unroll
    for (int rt = 0; rt < 4; rt++)
#pragma unroll
        for (int ct = 0; ct < 4; ct++)
#pragma unroll
            for (int r = 0; r < 4; r++)
                pl[w][(rt * 16 + lb * 4 + r) * 72 + ct * 16 + la] = f2bf(sa[rt][ct][r]);

    __syncthreads();

    f32x4 oa[4][2] = {};
#pragma unroll
    for (int ks = 0; ks < 2; ks++) {
        s16x8 vf[2];
#pragma unroll
        for (int dt = 0; dt < 2; dt++)
            vf[dt] = *(const s16x8*)&vt[w][(dt * 16 + la) * 72 + ks * 32 + lb * 8];
#pragma unroll
        for (int rt = 0; rt < 4; rt++) {
            s16x8 pf = *(const s16x8*)&pl[w][(rt * 16 + la) * 72 + ks * 32 + lb * 8];
#pragma unroll
            for (int dt = 0; dt < 2; dt++)
                oa[rt][dt] = __builtin_amdgcn_mfma_f32_16x16x32_bf16(pf, vf[dt], oa[rt][dt], 0, 0, 0);
        }
    }

#pragma unroll
    for (int rt = 0; rt < 4; rt++) {
#pragma unroll
        for (int r = 0; r < 4; r++) {
            int t = rt * 16 + lb * 4 + r;
            long sr = base_row + (t >> 3) * 64 + (t & 7);
#pragma unroll
            for (int dt = 0; dt < 2; dt++) {
                int d = dt * 16 + la;
                out[sr * 256 + h * 32 + d] = __float2bfloat16(oa[rt][dt][r] * rls[rt][r]);
            }
        }
    }
}

// ---------------------------------------------------------------------------
extern "C" void kernel_launch(void* const* d_in, const int* in_sizes, int n_in,
                              void* d_out, int out_size, void* d_ws, size_t ws_size,
                              hipStream_t stream) {
    const float* x_seq  = (const float*)d_in[0];
    const float* c      = (const float*)d_in[1];
    const float* qkv_w  = (const float*)d_in[2];
    const float* qkv_b  = (const float*)d_in[3];
    const float* proj_w = (const float*)d_in[4];
    const float* proj_b = (const float*)d_in[5];
    const float* rpb    = (const float*)d_in[6];
    const float* ada_w  = (const float*)d_in[7];
    const float* ada_b  = (const float*)d_in[8];
    const float* fc1_w  = (const float*)d_in[9];
    const float* fc1_b  = (const float*)d_in[10];
    const float* fc2_w  = (const float*)d_in[11];
    const float* fc2_b  = (const float*)d_in[12];

    char* ws = (char*)d_ws;
    float* ada             = (float*)ws;                       // 96 KB
    __hip_bfloat16* qkv_wt = (__hip_bfloat16*)(ws + 131072);   // 768x256 bf16
    __hip_bfloat16* proj_wt= (__hip_bfloat16*)(ws + 524288);   // 256x256
    __hip_bfloat16* fc1_wt = (__hip_bfloat16*)(ws + 655360);   // 1024x256
    __hip_bfloat16* fc2_wt = (__hip_bfloat16*)(ws + 1179648);  // 256x1024
    __hip_bfloat16* bufA   = (__hip_bfloat16*)(ws + 2097152);  // 32 MB: xb / attn_out
    __hip_bfloat16* bufB   = (__hip_bfloat16*)(ws + 35651584); // 128 MB: qkv
    float* outf = (float*)d_out;

    wconv_t<<<(256 * 768 + 255) / 256, 256, 0, stream>>>(qkv_w, qkv_wt, 256, 768);
    wconv_t<<<(256 * 256 + 255) / 256, 256, 0, stream>>>(proj_w, proj_wt, 256, 256);
    wconv_t<<<(256 * 1024 + 255) / 256, 256, 0, stream>>>(fc1_w, fc1_wt, 256, 1024);
    wconv_t<<<(1024 * 256 + 255) / 256, 256, 0, stream>>>(fc2_w, fc2_wt, 1024, 256);

    ada_kernel<<<6, 256, 0, stream>>>(c, ada_w, ada_b, ada);

    // x_win LN+modulate (MSA) -> bufA (bf16)
    ln_mod<<<TTOT / 4, 256, 0, stream>>>(x_seq, ada, 0, 256, bufA);

    // qkv = bufA @ qkv_w + b -> bufB (bf16, 65536 x 768); KM=4 M-stream
    {
        dim3 g(768 / 128, TTOT / (128 * 4));
        gemm_ms<0, 4><<<g, 256, 0, stream>>>(bufA, qkv_wt, qkv_b, nullptr, ada,
                                             nullptr, bufB, 768);
    }
    // window attention -> bufA (bf16, 65536 x 256)
    win_attn_mfma<<<2048, 256, 0, stream>>>(bufB, rpb, bufA);

    // out1 = x_seq + g_msa * (attn @ proj_w + b) -> d_out (f32); KM=2
    {
        dim3 g(256 / 128, TTOT / (128 * 2));
        gemm_ms<1, 2><<<g, 256, 0, stream>>>(bufA, proj_wt, proj_b, x_seq, ada,
                                             outf, nullptr, 256);
    }
    // fused MLP: LN+mod -> fc1 -> gelu -> fc2 -> out += g_mlp*h  (RMW d_out)
    mlp_fused<<<TTOT / 64, 256, 0, stream>>>(outf, fc1_wt, fc1_b, fc2_wt, fc2_b, ada);
}

// Round 10
// 407.169 us; speedup vs baseline: 1.0962x; 1.0962x over previous
//
#include <hip/hip_runtime.h>
#include <hip/hip_bf16.h>

#define TTOT 65536  // 16 * 4096 rows

using f32x4 = __attribute__((ext_vector_type(4))) float;
using s16x8 = __attribute__((ext_vector_type(8))) short;
typedef unsigned short u16;
using u16x8 = __attribute__((ext_vector_type(8))) u16;

typedef __attribute__((address_space(3))) void lds_void;
typedef __attribute__((address_space(1))) void g_void;

__device__ __forceinline__ float bf2f(u16 u) {
    union { unsigned int ui; float f; } v; v.ui = ((unsigned int)u) << 16; return v.f;
}

__device__ __forceinline__ u16 f2bf(float f) {
    return __bfloat16_as_ushort(__float2bfloat16(f));
}

// ---------------- weight transpose + bf16 convert: wt[n*K+k] = w[k*N+n] ----
__global__ void wconv_t(const float* __restrict__ w, __hip_bfloat16* __restrict__ wt,
                        int K, int N) {
    int idx = blockIdx.x * 256 + threadIdx.x;
    if (idx >= K * N) return;
    int n = idx / K, k = idx - n * K;
    wt[idx] = __float2bfloat16(w[(long)k * N + n]);
}

// ---------------- ada = silu(c) @ ada_w + ada_b   (16 x 1536) --------------
__global__ __launch_bounds__(256) void ada_kernel(const float* __restrict__ c,
                                                  const float* __restrict__ ada_w,
                                                  const float* __restrict__ ada_b,
                                                  float* __restrict__ ada) {
    __shared__ float sc[16 * 256];
    int tid = threadIdx.x;
    for (int i = tid; i < 16 * 256; i += 256) {
        float v = c[i];
        sc[i] = v / (1.0f + expf(-v));
    }
    __syncthreads();
    int j = blockIdx.x * 256 + tid;   // grid = 6 -> j in [0,1536)
    float b = ada_b[j];
    for (int n = 0; n < 16; n++) {
        float acc = b;
        for (int k = 0; k < 256; k++)
            acc += sc[n * 256 + k] * ada_w[(long)k * 1536 + j];
        ada[n * 1536 + j] = acc;
    }
}

// ---------------- fused LayerNorm + modulate -> bf16 -----------------------
__global__ __launch_bounds__(256) void ln_mod(const float* __restrict__ x,
                                              const float* __restrict__ ada,
                                              int off_sh, int off_sc,
                                              __hip_bfloat16* __restrict__ out) {
    int row = blockIdx.x * 4 + (threadIdx.x >> 6);
    int lane = threadIdx.x & 63;
    const float4 v = *(const float4*)&x[(long)row * 256 + lane * 4];
    float s = v.x + v.y + v.z + v.w;
    float s2 = v.x * v.x + v.y * v.y + v.z * v.z + v.w * v.w;
#pragma unroll
    for (int o = 32; o > 0; o >>= 1) {
        s += __shfl_xor(s, o, 64);
        s2 += __shfl_xor(s2, o, 64);
    }
    float mu = s * (1.0f / 256.0f);
    float var = s2 * (1.0f / 256.0f) - mu * mu;
    float rstd = rsqrtf(var + 1e-6f);
    int nb = row >> 12;
    const float* sh = &ada[nb * 1536 + off_sh];
    const float* scp = &ada[nb * 1536 + off_sc];
    float vv[4] = {v.x, v.y, v.z, v.w};
#pragma unroll
    for (int e = 0; e < 4; e++) {
        int col = lane * 4 + e;
        float val = (vv[e] - mu) * rstd;
        val = val * (1.0f + scp[col]) + sh[col];
        out[(long)row * 256 + col] = __float2bfloat16(val);
    }
}

// ---------------- bf16 MFMA GEMM (round-4 structure, best measured) --------
// 2-phase dbuf pipeline (counted vmcnt), XOR-swizzled LDS, wave-uniform DMA.
// MODE 0: qkv   -> outb = acc + bias                        (bf16)
// MODE 1: proj  -> outf = resid + g_msa * (acc + bias)      (f32, d_out)
template <int MODE>
__global__ __launch_bounds__(256) void gemm_bt(const __hip_bfloat16* __restrict__ A,
                                               const __hip_bfloat16* __restrict__ Bt,
                                               const float* __restrict__ bias,
                                               const float* __restrict__ resid,
                                               const float* __restrict__ ada,
                                               float* __restrict__ outf,
                                               __hip_bfloat16* __restrict__ outb,
                                               int M, int N, int K) {
    __shared__ u16 As[2][128 * 64];   // linear dest (global_load_lds), swizzled content
    __shared__ u16 Bs[2][128 * 64];
    int tid = threadIdx.x;
    int lane = tid & 63;
    int wid = tid >> 6;
    int wr = wid >> 1, wc = wid & 1;
    int brow = blockIdx.y * 128;
    int bcol = blockIdx.x * 128;
    int la = lane & 15, lb = lane >> 4;

    f32x4 acc[4][4] = {};

    const u16* Ag = (const u16*)A;
    const u16* Bg = (const u16*)Bt;

    auto STAGE = [&](int k0, int buf) {
#pragma unroll
        for (int i = 0; i < 4; i++) {
            int c = (wid * 4 + i) * 64 + lane;   // 16B chunk id, 0..1023
            int row = c >> 3;
            int sc = (c & 7) ^ (row & 7);        // inverse-swizzled source chunk
            __builtin_amdgcn_global_load_lds(
                (const g_void*)(Ag + (long)(brow + row) * K + k0 + sc * 8),
                (lds_void*)&As[buf][(wid * 4 + i) * 512], 16, 0, 0);
            __builtin_amdgcn_global_load_lds(
                (const g_void*)(Bg + (long)(bcol + row) * K + k0 + sc * 8),
                (lds_void*)&Bs[buf][(wid * 4 + i) * 512], 16, 0, 0);
        }
    };

    int NT = K >> 6;
    STAGE(0, 0);
    for (int t = 0; t < NT; ++t) {
        int cur = t & 1;
        if (t + 1 < NT) {
            STAGE((t + 1) << 6, cur ^ 1);
            asm volatile("s_waitcnt vmcnt(8)" ::: "memory");   // tile t landed
        } else {
            asm volatile("s_waitcnt vmcnt(0)" ::: "memory");
        }
        __builtin_amdgcn_s_barrier();   // tile t visible to all waves
#pragma unroll
        for (int kk8 = 0; kk8 < 8; kk8 += 4) {   // kk = kk8*8 in {0,32}
            s16x8 af[4], bfr[4];
#pragma unroll
            for (int m = 0; m < 4; m++) {
                int R = wr * 64 + m * 16 + la;
                af[m] = *(const s16x8*)&As[cur][R * 64 + (((kk8 + lb) ^ (R & 7)) << 3)];
            }
#pragma unroll
            for (int n2 = 0; n2 < 4; n2++) {
                int R = wc * 64 + n2 * 16 + la;
                bfr[n2] = *(const s16x8*)&Bs[cur][R * 64 + (((kk8 + lb) ^ (R & 7)) << 3)];
            }
#pragma unroll
            for (int m = 0; m < 4; m++)
#pragma unroll
                for (int n2 = 0; n2 < 4; n2++)
                    acc[m][n2] = __builtin_amdgcn_mfma_f32_16x16x32_bf16(
                        af[m], bfr[n2], acc[m][n2], 0, 0, 0);
        }
        __builtin_amdgcn_s_barrier();   // reads done before buffer reuse
    }

    int nb = brow >> 12;
#pragma unroll
    for (int m = 0; m < 4; m++) {
#pragma unroll
        for (int n2 = 0; n2 < 4; n2++) {
#pragma unroll
            for (int r = 0; r < 4; r++) {
                int row = brow + wr * 64 + m * 16 + lb * 4 + r;
                int col = bcol + wc * 64 + n2 * 16 + la;
                float v = acc[m][n2][r] + bias[col];
                long oidx = (long)row * N + col;
                if (MODE == 0) {
                    outb[oidx] = __float2bfloat16(v);
                } else {
                    float g = ada[nb * 1536 + 512 + col];
                    outf[oidx] = resid[oidx] + g * v;
                }
            }
        }
    }
}

// ---------------- fused MLP (v1 + hb stride 268 + setprio) -----------------
// Block = 256 thr / 4 waves, 64-row panel, HID chunks of 256.
// h1 never touches HBM. hb stride 268 u16: gelu-store lb-rows land at banks
// {0,24,16,8} with disjoint 8-dword spans -> conflict-free (was 4.2M @264).
__global__ __launch_bounds__(256, 2) void mlp_fused(float* __restrict__ outf,
                                                    const __hip_bfloat16* __restrict__ fc1w,
                                                    const float* __restrict__ fc1_b,
                                                    const __hip_bfloat16* __restrict__ fc2w,
                                                    const float* __restrict__ fc2_b,
                                                    const float* __restrict__ ada) {
    __shared__ u16 xa[64 * 264];   // LN+mod rows, bf16, stride 264 (reads 2-way max)
    __shared__ u16 hb[64 * 268];   // gelu(h1) chunk, bf16, stride 268 (store-conflict-free)

    int tid = threadIdx.x;
    int lane = tid & 63;
    int w = tid >> 6;              // wave 0..3: owns n-slice [w*64, +64)
    int la = lane & 15, lb = lane >> 4;
    long mrow = (long)blockIdx.x * 64;
    int nb = (int)(mrow >> 12);

    const u16* F1 = (const u16*)fc1w;   // [1024][256]
    const u16* F2 = (const u16*)fc2w;   // [256][1024]

    // ---- Phase 0: LN + modulate (MLP branch) out1 -> xa ----
    const float* sh = &ada[nb * 1536 + 768];
    const float* scp = &ada[nb * 1536 + 1024];
#pragma unroll
    for (int i = 0; i < 16; i++) {
        int row = i * 4 + w;
        const float4 v = *(const float4*)&outf[(mrow + row) * 256 + lane * 4];
        float s = v.x + v.y + v.z + v.w;
        float s2 = v.x * v.x + v.y * v.y + v.z * v.z + v.w * v.w;
#pragma unroll
        for (int o = 32; o > 0; o >>= 1) {
            s += __shfl_xor(s, o, 64);
            s2 += __shfl_xor(s2, o, 64);
        }
        float mu = s * (1.0f / 256.0f);
        float var = s2 * (1.0f / 256.0f) - mu * mu;
        float rstd = rsqrtf(var + 1e-6f);
        float vv[4] = {v.x, v.y, v.z, v.w};
#pragma unroll
        for (int e = 0; e < 4; e++) {
            int col = lane * 4 + e;
            float val = (vv[e] - mu) * rstd;
            val = val * (1.0f + scp[col]) + sh[col];
            xa[row * 264 + col] = f2bf(val);
        }
    }
    __syncthreads();

    f32x4 acc2[4][4] = {};

#pragma unroll 1
    for (int c = 0; c < 4; c++) {
        // ---- GEMM1: acc1 = xa @ fc1_w[:, c*256 + w*64 ...] ----
        f32x4 acc1[4][4] = {};
        const u16* B1 = F1 + (long)(c * 256 + w * 64) * 256;
        s16x8 bc[8];
#pragma unroll
        for (int ct = 0; ct < 4; ct++)
#pragma unroll
            for (int kk = 0; kk < 2; kk++)
                bc[ct * 2 + kk] = *(const s16x8*)&B1[(ct * 16 + la) * 256 + kk * 32 + lb * 8];
#pragma unroll
        for (int k0 = 0; k0 < 4; k0++) {
            s16x8 bn[8];
            if (k0 < 3) {
#pragma unroll
                for (int ct = 0; ct < 4; ct++)
#pragma unroll
                    for (int kk = 0; kk < 2; kk++)
                        bn[ct * 2 + kk] = *(const s16x8*)&B1[(ct * 16 + la) * 256 +
                                                             (k0 + 1) * 64 + kk * 32 + lb * 8];
            }
            s16x8 a[4][2];
#pragma unroll
            for (int rt = 0; rt < 4; rt++)
#pragma unroll
                for (int kk = 0; kk < 2; kk++)
                    a[rt][kk] = *(const s16x8*)&xa[(rt * 16 + la) * 264 +
                                                   k0 * 64 + kk * 32 + lb * 8];
            __builtin_amdgcn_s_setprio(1);
#pragma unroll
            for (int kk = 0; kk < 2; kk++)
#pragma unroll
                for (int rt = 0; rt < 4; rt++)
#pragma unroll
                    for (int ct = 0; ct < 4; ct++)
                        acc1[rt][ct] = __builtin_amdgcn_mfma_f32_16x16x32_bf16(
                            a[rt][kk], bc[ct * 2 + kk], acc1[rt][ct], 0, 0, 0);
            __builtin_amdgcn_s_setprio(0);
            if (k0 < 3) {
#pragma unroll
                for (int q = 0; q < 8; q++) bc[q] = bn[q];
            }
        }
        // ---- gelu + write hb ----
#pragma unroll
        for (int ct = 0; ct < 4; ct++) {
            float b1v = fc1_b[c * 256 + w * 64 + ct * 16 + la];
#pragma unroll
            for (int rt = 0; rt < 4; rt++) {
#pragma unroll
                for (int r = 0; r < 4; r++) {
                    float v = acc1[rt][ct][r] + b1v;
                    float u2 = 1.5957691216057308f * (v + 0.044715f * v * v * v);
                    hb[(rt * 16 + lb * 4 + r) * 268 + w * 64 + ct * 16 + la] =
                        f2bf(v / (1.0f + __expf(-u2)));
                }
            }
        }
        __syncthreads();   // hb(c) complete before GEMM2 reads

        // ---- GEMM2: acc2 += hb @ fc2_w[:, k-chunk c] ----
        const u16* B2 = F2 + (long)(w * 64) * 1024 + c * 256;
        s16x8 bc2[8];
#pragma unroll
        for (int ct = 0; ct < 4; ct++)
#pragma unroll
            for (int kk = 0; kk < 2; kk++)
                bc2[ct * 2 + kk] = *(const s16x8*)&B2[(ct * 16 + la) * 1024 + kk * 32 + lb * 8];
#pragma unroll
        for (int k0 = 0; k0 < 4; k0++) {
            s16x8 bn2[8];
            if (k0 < 3) {
#pragma unroll
                for (int ct = 0; ct < 4; ct++)
#pragma unroll
                    for (int kk = 0; kk < 2; kk++)
                        bn2[ct * 2 + kk] = *(const s16x8*)&B2[(ct * 16 + la) * 1024 +
                                                              (k0 + 1) * 64 + kk * 32 + lb * 8];
            }
            s16x8 a[4][2];
#pragma unroll
            for (int rt = 0; rt < 4; rt++)
#pragma unroll
                for (int kk = 0; kk < 2; kk++)
                    a[rt][kk] = *(const s16x8*)&hb[(rt * 16 + la) * 268 +
                                                   k0 * 64 + kk * 32 + lb * 8];
            __builtin_amdgcn_s_setprio(1);
#pragma unroll
            for (int kk = 0; kk < 2; kk++)
#pragma unroll
                for (int rt = 0; rt < 4; rt++)
#pragma unroll
                    for (int ct = 0; ct < 4; ct++)
                        acc2[rt][ct] = __builtin_amdgcn_mfma_f32_16x16x32_bf16(
                            a[rt][kk], bc2[ct * 2 + kk], acc2[rt][ct], 0, 0, 0);
            __builtin_amdgcn_s_setprio(0);
            if (k0 < 3) {
#pragma unroll
                for (int q = 0; q < 8; q++) bc2[q] = bn2[q];
            }
        }
        __syncthreads();   // GEMM2 reads done before next chunk's hb write
    }

    // ---- epilogue: out = out1 + g_mlp * (acc2 + fc2_b) ----
#pragma unroll
    for (int ct = 0; ct < 4; ct++) {
        int col = w * 64 + ct * 16 + la;
        float g = ada[nb * 1536 + 1280 + col];
        float b2v = fc2_b[col];
#pragma unroll
        for (int rt = 0; rt < 4; rt++) {
#pragma unroll
            for (int r = 0; r < 4; r++) {
                long row = mrow + rt * 16 + lb * 4 + r;
                long oidx = row * 256 + col;
                outf[oidx] = outf[oidx] + g * (acc2[rt][ct][r] + b2v);
            }
        }
    }
}

// ---------------- MFMA window attention ------------------------------------
__global__ __launch_bounds__(256) void win_attn_mfma(const __hip_bfloat16* __restrict__ qkv,
                                                     const float* __restrict__ rpb,
                                                     __hip_bfloat16* __restrict__ out) {
    __shared__ float bias_s[64 * 64];
    __shared__ u16 vt[4][32 * 72];
    __shared__ u16 pl[4][64 * 72];

    int tid = threadIdx.x;
    int bid = blockIdx.x;
    int h = bid & 7;
    int w = tid >> 6;
    int lane = tid & 63;
    int la = lane & 15, lb = lane >> 4;
    int win = (bid >> 3) * 4 + w;
    int n = win >> 6;
    int wh = (win >> 3) & 7;
    int ww = win & 7;
    long base_row = (long)n * 4096 + (long)(wh * 8) * 64 + ww * 8;

    for (int i = tid; i < 4096; i += 256) {
        int t = i >> 6, j = i & 63;
        int idx = ((t >> 3) - (j >> 3) + 7) * 15 + ((t & 7) - (j & 7) + 7);
        bias_s[i] = rpb[idx * 8 + h];
    }

    const u16* qg = (const u16*)qkv;

    s16x8 qf[4], kf[4];
#pragma unroll
    for (int rt = 0; rt < 4; rt++) {
        int t = rt * 16 + la;
        long sr = base_row + (t >> 3) * 64 + (t & 7);
        qf[rt] = *(const s16x8*)(qg + sr * 768 + h * 32 + lb * 8);
        kf[rt] = *(const s16x8*)(qg + sr * 768 + 256 + h * 32 + lb * 8);
    }
#pragma unroll
    for (int g = 0; g < 4; g++) {
        int t = g * 16 + la;
        long sr = base_row + (t >> 3) * 64 + (t & 7);
        u16x8 vv = *(const u16x8*)(qg + sr * 768 + 512 + h * 32 + lb * 8);
#pragma unroll
        for (int e = 0; e < 8; e++) vt[w][(lb * 8 + e) * 72 + t] = vv[e];
    }

    f32x4 sa[4][4];
    f32x4 zero = {};
#pragma unroll
    for (int rt = 0; rt < 4; rt++)
#pragma unroll
        for (int ct = 0; ct < 4; ct++)
            sa[rt][ct] = __builtin_amdgcn_mfma_f32_16x16x32_bf16(qf[rt], kf[ct], zero, 0, 0, 0);

    __syncthreads();

    float rls[4][4];
#pragma unroll
    for (int rt = 0; rt < 4; rt++) {
#pragma unroll
        for (int r = 0; r < 4; r++) {
            int t = rt * 16 + lb * 4 + r;
            float v0 = sa[rt][0][r] * 0.17677669529663687f + bias_s[t * 64 + 0 * 16 + la];
            float v1 = sa[rt][1][r] * 0.17677669529663687f + bias_s[t * 64 + 1 * 16 + la];
            float v2 = sa[rt][2][r] * 0.17677669529663687f + bias_s[t * 64 + 2 * 16 + la];
            float v3 = sa[rt][3][r] * 0.17677669529663687f + bias_s[t * 64 + 3 * 16 + la];
            float mx = fmaxf(fmaxf(v0, v1), fmaxf(v2, v3));
#pragma unroll
            for (int o = 1; o < 16; o <<= 1) mx = fmaxf(mx, __shfl_xor(mx, o, 64));
            float p0 = __expf(v0 - mx), p1 = __expf(v1 - mx);
            float p2 = __expf(v2 - mx), p3 = __expf(v3 - mx);
            float sum = (p0 + p1) + (p2 + p3);
#pragma unroll
            for (int o = 1; o < 16; o <<= 1) sum += __shfl_xor(sum, o, 64);
            sa[rt][0][r] = p0; sa[rt][1][r] = p1; sa[rt][2][r] = p2; sa[rt][3][r] = p3;
            rls[rt][r] = 1.0f / sum;
        }
    }

#pragma unroll
    for (int rt = 0; rt < 4; rt++)
#pragma unroll
        for (int ct = 0; ct < 4; ct++)
#pragma unroll
            for (int r = 0; r < 4; r++)
                pl[w][(rt * 16 + lb * 4 + r) * 72 + ct * 16 + la] = f2bf(sa[rt][ct][r]);

    __syncthreads();

    f32x4 oa[4][2] = {};
#pragma unroll
    for (int ks = 0; ks < 2; ks++) {
        s16x8 vf[2];
#pragma unroll
        for (int dt = 0; dt < 2; dt++)
            vf[dt] = *(const s16x8*)&vt[w][(dt * 16 + la) * 72 + ks * 32 + lb * 8];
#pragma unroll
        for (int rt = 0; rt < 4; rt++) {
            s16x8 pf = *(const s16x8*)&pl[w][(rt * 16 + la) * 72 + ks * 32 + lb * 8];
#pragma unroll
            for (int dt = 0; dt < 2; dt++)
                oa[rt][dt] = __builtin_amdgcn_mfma_f32_16x16x32_bf16(pf, vf[dt], oa[rt][dt], 0, 0, 0);
        }
    }

#pragma unroll
    for (int rt = 0; rt < 4; rt++) {
#pragma unroll
        for (int r = 0; r < 4; r++) {
            int t = rt * 16 + lb * 4 + r;
            long sr = base_row + (t >> 3) * 64 + (t & 7);
#pragma unroll
            for (int dt = 0; dt < 2; dt++) {
                int d = dt * 16 + la;
                out[sr * 256 + h * 32 + d] = __float2bfloat16(oa[rt][dt][r] * rls[rt][r]);
            }
        }
    }
}

// ---------------------------------------------------------------------------
extern "C" void kernel_launch(void* const* d_in, const int* in_sizes, int n_in,
                              void* d_out, int out_size, void* d_ws, size_t ws_size,
                              hipStream_t stream) {
    const float* x_seq  = (const float*)d_in[0];
    const float* c      = (const float*)d_in[1];
    const float* qkv_w  = (const float*)d_in[2];
    const float* qkv_b  = (const float*)d_in[3];
    const float* proj_w = (const float*)d_in[4];
    const float* proj_b = (const float*)d_in[5];
    const float* rpb    = (const float*)d_in[6];
    const float* ada_w  = (const float*)d_in[7];
    const float* ada_b  = (const float*)d_in[8];
    const float* fc1_w  = (const float*)d_in[9];
    const float* fc1_b  = (const float*)d_in[10];
    const float* fc2_w  = (const float*)d_in[11];
    const float* fc2_b  = (const float*)d_in[12];

    char* ws = (char*)d_ws;
    float* ada             = (float*)ws;                       // 96 KB
    __hip_bfloat16* qkv_wt = (__hip_bfloat16*)(ws + 131072);   // 768x256 bf16
    __hip_bfloat16* proj_wt= (__hip_bfloat16*)(ws + 524288);   // 256x256
    __hip_bfloat16* fc1_wt = (__hip_bfloat16*)(ws + 655360);   // 1024x256
    __hip_bfloat16* fc2_wt = (__hip_bfloat16*)(ws + 1179648);  // 256x1024
    __hip_bfloat16* bufA   = (__hip_bfloat16*)(ws + 2097152);  // 32 MB: xb / attn_out
    __hip_bfloat16* bufB   = (__hip_bfloat16*)(ws + 35651584); // 128 MB: qkv
    float* outf = (float*)d_out;

    wconv_t<<<(256 * 768 + 255) / 256, 256, 0, stream>>>(qkv_w, qkv_wt, 256, 768);
    wconv_t<<<(256 * 256 + 255) / 256, 256, 0, stream>>>(proj_w, proj_wt, 256, 256);
    wconv_t<<<(256 * 1024 + 255) / 256, 256, 0, stream>>>(fc1_w, fc1_wt, 256, 1024);
    wconv_t<<<(1024 * 256 + 255) / 256, 256, 0, stream>>>(fc2_w, fc2_wt, 1024, 256);

    ada_kernel<<<6, 256, 0, stream>>>(c, ada_w, ada_b, ada);

    // x_win LN+modulate (MSA) -> bufA (bf16)
    ln_mod<<<TTOT / 4, 256, 0, stream>>>(x_seq, ada, 0, 256, bufA);

    // qkv = bufA @ qkv_w + b -> bufB (bf16, 65536 x 768)
    {
        dim3 g(768 / 128, TTOT / 128);
        gemm_bt<0><<<g, 256, 0, stream>>>(bufA, qkv_wt, qkv_b, nullptr, ada,
                                          nullptr, bufB, TTOT, 768, 256);
    }
    // window attention -> bufA (bf16, 65536 x 256)
    win_attn_mfma<<<2048, 256, 0, stream>>>(bufB, rpb, bufA);

    // out1 = x_seq + g_msa * (attn @ proj_w + b) -> d_out (f32)
    {
        dim3 g(256 / 128, TTOT / 128);
        gemm_bt<1><<<g, 256, 0, stream>>>(bufA, proj_wt, proj_b, x_seq, ada,
                                          outf, nullptr, TTOT, 256, 256);
    }
    // fused MLP: LN+mod -> fc1 -> gelu -> fc2 -> out += g_mlp*h  (RMW d_out)
    mlp_fused<<<TTOT / 64, 256, 0, stream>>>(outf, fc1_wt, fc1_b, fc2_wt, fc2_b, ada);
}

// Round 11
// 361.210 us; speedup vs baseline: 1.2357x; 1.1272x over previous
//
#include <hip/hip_runtime.h>
#include <hip/hip_bf16.h>

#define TTOT 65536  // 16 * 4096 rows

using f32x4 = __attribute__((ext_vector_type(4))) float;
using s16x8 = __attribute__((ext_vector_type(8))) short;
typedef unsigned short u16;
using u16x8 = __attribute__((ext_vector_type(8))) u16;

__device__ __forceinline__ u16 f2bf(float f) {
    return __bfloat16_as_ushort(__float2bfloat16(f));
}

// ---------------- weight transpose + bf16 convert: wt[n*K+k] = w[k*N+n] ----
__global__ void wconv_t(const float* __restrict__ w, __hip_bfloat16* __restrict__ wt,
                        int K, int N) {
    int idx = blockIdx.x * 256 + threadIdx.x;
    if (idx >= K * N) return;
    int n = idx / K, k = idx - n * K;
    wt[idx] = __float2bfloat16(w[(long)k * N + n]);
}

// ---------------- ada = silu(c) @ ada_w + ada_b   (16 x 1536) --------------
__global__ __launch_bounds__(256) void ada_kernel(const float* __restrict__ c,
                                                  const float* __restrict__ ada_w,
                                                  const float* __restrict__ ada_b,
                                                  float* __restrict__ ada) {
    __shared__ float sc[16 * 256];
    int tid = threadIdx.x;
    for (int i = tid; i < 16 * 256; i += 256) {
        float v = c[i];
        sc[i] = v / (1.0f + expf(-v));
    }
    __syncthreads();
    int j = blockIdx.x * 256 + tid;   // grid = 6 -> j in [0,1536)
    float b = ada_b[j];
    for (int n = 0; n < 16; n++) {
        float acc = b;
        for (int k = 0; k < 256; k++)
            acc += sc[n * 256 + k] * ada_w[(long)k * 1536 + j];
        ada[n * 1536 + j] = acc;
    }
}

// ---------------- mega attention: LN -> QKV -> attn -> proj -> residual ----
// Block = 1 window (64 tokens), 8 waves = 8 heads. Everything window-local
// stays in LDS/registers; only x_seq read + out1 write touch HBM.
// LDS: xa (x LN'd, later O) 33.8K | qk (Q|K, later per-wave P) 67.6K |
//      vt 36.9K | bias 7.2K = 145.4 KB -> 1 block/CU, 8 waves.
__global__ __launch_bounds__(512) void attn_mega(const float* __restrict__ x_seq,
                                                 const __hip_bfloat16* __restrict__ qkvw,
                                                 const float* __restrict__ qkv_b,
                                                 const __hip_bfloat16* __restrict__ projw,
                                                 const float* __restrict__ proj_b,
                                                 const float* __restrict__ rpb,
                                                 const float* __restrict__ ada,
                                                 float* __restrict__ outf) {
    __shared__ u16 xa[64 * 264];     // LN'd x ; reused for O after barrier
    __shared__ u16 qk[2 * 64 * 264]; // Q [0,16896) K [16896,33792) ; later P_h at h*4096
    __shared__ u16 vt[8][32 * 72];   // per-head V^T
    __shared__ float bs[8 * 225];    // compact rel-pos bias per head

    int tid = threadIdx.x;
    int lane = tid & 63;
    int h = tid >> 6;                // wave == head
    int la = lane & 15, lb = lane >> 4;
    int win = blockIdx.x;
    int n = win >> 6, wh = (win >> 3) & 7, ww = win & 7;
    long base = (long)n * 4096 + (long)(wh * 8) * 64 + ww * 8;
    // seqrow(t) = base + (t>>3)*64 + (t&7)

    for (int i = tid; i < 1800; i += 512) bs[i] = rpb[(i % 225) * 8 + (i / 225)];

    // ---- LN + modulate (MSA): wave h owns window rows t = h*8 .. h*8+7 ----
    {
        const float* shp = &ada[n * 1536 + 0];
        const float* scp = &ada[n * 1536 + 256];
#pragma unroll
        for (int i = 0; i < 8; i++) {
            int t = h * 8 + i;
            long sr = base + h * 64 + i;
            const float4 v = *(const float4*)&x_seq[sr * 256 + lane * 4];
            float s = v.x + v.y + v.z + v.w;
            float s2 = v.x * v.x + v.y * v.y + v.z * v.z + v.w * v.w;
#pragma unroll
            for (int o = 32; o > 0; o >>= 1) {
                s += __shfl_xor(s, o, 64);
                s2 += __shfl_xor(s2, o, 64);
            }
            float mu = s * (1.0f / 256.0f);
            float var = s2 * (1.0f / 256.0f) - mu * mu;
            float rstd = rsqrtf(var + 1e-6f);
            float vv[4] = {v.x, v.y, v.z, v.w};
#pragma unroll
            for (int e = 0; e < 4; e++) {
                int col = lane * 4 + e;
                float val = (vv[e] - mu) * rstd;
                xa[t * 264 + col] = f2bf(val * (1.0f + scp[col]) + shp[col]);
            }
        }
    }
    __syncthreads();   // xa ready for all waves

    const u16* W = (const u16*)qkvw;   // [768][256]

    // ---- Q, K -> qk LDS ; V -> vt LDS (all wave-local GEMMs, 64 MFMA ea) --
#pragma unroll
    for (int m = 0; m < 3; m++) {
        const u16* Wm = W + (long)(m * 256 + h * 32) * 256;
        float bb0 = qkv_b[m * 256 + h * 32 + la];
        float bb1 = qkv_b[m * 256 + h * 32 + 16 + la];
        s16x8 bfr[2][8];
#pragma unroll
        for (int ct = 0; ct < 2; ct++)
#pragma unroll
            for (int kc = 0; kc < 8; kc++)
                bfr[ct][kc] = *(const s16x8*)&Wm[(ct * 16 + la) * 256 + kc * 32 + lb * 8];
        f32x4 acc[4][2] = {};
#pragma unroll
        for (int kc = 0; kc < 8; kc++) {
            s16x8 a[4];
#pragma unroll
            for (int rt = 0; rt < 4; rt++)
                a[rt] = *(const s16x8*)&xa[(rt * 16 + la) * 264 + kc * 32 + lb * 8];
#pragma unroll
            for (int rt = 0; rt < 4; rt++)
#pragma unroll
                for (int ct = 0; ct < 2; ct++)
                    acc[rt][ct] = __builtin_amdgcn_mfma_f32_16x16x32_bf16(
                        a[rt], bfr[ct][kc], acc[rt][ct], 0, 0, 0);
        }
        if (m < 2) {
            u16* dst = &qk[m * 16896];
#pragma unroll
            for (int rt = 0; rt < 4; rt++)
#pragma unroll
                for (int ct = 0; ct < 2; ct++)
#pragma unroll
                    for (int r = 0; r < 4; r++)
                        dst[(rt * 16 + lb * 4 + r) * 264 + h * 32 + ct * 16 + la] =
                            f2bf(acc[rt][ct][r] + (ct ? bb1 : bb0));
        } else {
#pragma unroll
            for (int rt = 0; rt < 4; rt++)
#pragma unroll
                for (int ct = 0; ct < 2; ct++)
#pragma unroll
                    for (int r = 0; r < 4; r++)
                        vt[h][(ct * 16 + la) * 72 + rt * 16 + lb * 4 + r] =
                            f2bf(acc[rt][ct][r] + (ct ? bb1 : bb0));
        }
    }
    __syncthreads();   // Q/K/V staged (also drains lgkm for own-wave reads)

    // ---- S = Q K^T (frags from LDS, wave-local) ----
    s16x8 qf[4], kf[4];
#pragma unroll
    for (int rt = 0; rt < 4; rt++) {
        qf[rt] = *(const s16x8*)&qk[(rt * 16 + la) * 264 + h * 32 + lb * 8];
        kf[rt] = *(const s16x8*)&qk[16896 + (rt * 16 + la) * 264 + h * 32 + lb * 8];
    }
    f32x4 sa[4][4];
    f32x4 zero = {};
#pragma unroll
    for (int rt = 0; rt < 4; rt++)
#pragma unroll
        for (int ct = 0; ct < 4; ct++)
            sa[rt][ct] = __builtin_amdgcn_mfma_f32_16x16x32_bf16(qf[rt], kf[ct], zero, 0, 0, 0);

    // ---- softmax (rows t = rt*16+lb*4+r, keys j = ct*16+la) ----
    float rls[4][4];
    int jr = (la >> 3);        // + ct*2
    int jc = la & 7;
#pragma unroll
    for (int rt = 0; rt < 4; rt++) {
#pragma unroll
        for (int r = 0; r < 4; r++) {
            int t = rt * 16 + lb * 4 + r;
            int tr = t >> 3, tc = t & 7;
            const float* bh = &bs[h * 225 + (tr + 7) * 15 + (tc - jc + 7)];
            float v0 = sa[rt][0][r] * 0.17677669529663687f + bh[-(0 * 2 + jr) * 15];
            float v1 = sa[rt][1][r] * 0.17677669529663687f + bh[-(1 * 2 + jr) * 15];
            float v2 = sa[rt][2][r] * 0.17677669529663687f + bh[-(2 * 2 + jr) * 15];
            float v3 = sa[rt][3][r] * 0.17677669529663687f + bh[-(3 * 2 + jr) * 15];
            float mx = fmaxf(fmaxf(v0, v1), fmaxf(v2, v3));
#pragma unroll
            for (int o = 1; o < 16; o <<= 1) mx = fmaxf(mx, __shfl_xor(mx, o, 64));
            float p0 = __expf(v0 - mx), p1 = __expf(v1 - mx);
            float p2 = __expf(v2 - mx), p3 = __expf(v3 - mx);
            float sum = (p0 + p1) + (p2 + p3);
#pragma unroll
            for (int o = 1; o < 16; o <<= 1) sum += __shfl_xor(sum, o, 64);
            sa[rt][0][r] = p0; sa[rt][1][r] = p1; sa[rt][2][r] = p2; sa[rt][3][r] = p3;
            rls[rt][r] = 1.0f / sum;
        }
    }
    __syncthreads();   // all waves done reading Q/K -> region reusable for P

    // ---- P -> qk region (per-wave 8KB, XOR-swizzled linear [64][64]) ----
    u16* P = &qk[h * 4096];
#pragma unroll
    for (int rt = 0; rt < 4; rt++)
#pragma unroll
        for (int ct = 0; ct < 4; ct++)
#pragma unroll
            for (int r = 0; r < 4; r++) {
                int t = rt * 16 + lb * 4 + r;
                int slot = ct * 2 + (la >> 3);
                P[t * 64 + ((slot ^ (t & 7)) << 3) + (la & 7)] = f2bf(sa[rt][ct][r]);
            }
    __syncthreads();   // P visible (covers own-wave lgkm ordering too)

    // ---- O = P V ----
    f32x4 oa[4][2] = {};
#pragma unroll
    for (int ks = 0; ks < 2; ks++) {
        s16x8 vf[2];
#pragma unroll
        for (int dt = 0; dt < 2; dt++)
            vf[dt] = *(const s16x8*)&vt[h][(dt * 16 + la) * 72 + ks * 32 + lb * 8];
#pragma unroll
        for (int rt = 0; rt < 4; rt++) {
            int t = rt * 16 + la;
            s16x8 pf = *(const s16x8*)&P[t * 64 + (((ks * 4 + lb) ^ (t & 7)) << 3)];
#pragma unroll
            for (int dt = 0; dt < 2; dt++)
                oa[rt][dt] = __builtin_amdgcn_mfma_f32_16x16x32_bf16(pf, vf[dt], oa[rt][dt], 0, 0, 0);
        }
    }
    // stage O (normalized) into xa region (x reads finished pre-P barrier)
#pragma unroll
    for (int rt = 0; rt < 4; rt++)
#pragma unroll
        for (int dt = 0; dt < 2; dt++)
#pragma unroll
            for (int r = 0; r < 4; r++)
                xa[(rt * 16 + lb * 4 + r) * 264 + h * 32 + dt * 16 + la] =
                    f2bf(oa[rt][dt][r] * rls[rt][r]);
    __syncthreads();   // full O (all heads) ready

    // ---- proj: out cols [h*32, h*32+32), K = 256 over all heads' O ----
    {
        const u16* Pw = (const u16*)projw + (long)(h * 32) * 256;
        s16x8 bfr[2][8];
#pragma unroll
        for (int ct = 0; ct < 2; ct++)
#pragma unroll
            for (int kc = 0; kc < 8; kc++)
                bfr[ct][kc] = *(const s16x8*)&Pw[(ct * 16 + la) * 256 + kc * 32 + lb * 8];
        f32x4 pj[4][2] = {};
#pragma unroll
        for (int kc = 0; kc < 8; kc++) {
            s16x8 a[4];
#pragma unroll
            for (int rt = 0; rt < 4; rt++)
                a[rt] = *(const s16x8*)&xa[(rt * 16 + la) * 264 + kc * 32 + lb * 8];
#pragma unroll
            for (int rt = 0; rt < 4; rt++)
#pragma unroll
                for (int ct = 0; ct < 2; ct++)
                    pj[rt][ct] = __builtin_amdgcn_mfma_f32_16x16x32_bf16(
                        a[rt], bfr[ct][kc], pj[rt][ct], 0, 0, 0);
        }
        // epilogue: out1 = x_seq + g_msa * (pj + proj_b)
        float g0 = ada[n * 1536 + 512 + h * 32 + la];
        float g1 = ada[n * 1536 + 512 + h * 32 + 16 + la];
        float pb0 = proj_b[h * 32 + la];
        float pb1 = proj_b[h * 32 + 16 + la];
#pragma unroll
        for (int rt = 0; rt < 4; rt++) {
#pragma unroll
            for (int r = 0; r < 4; r++) {
                int t = rt * 16 + lb * 4 + r;
                long sr = base + (t >> 3) * 64 + (t & 7);
#pragma unroll
                for (int ct = 0; ct < 2; ct++) {
                    int col = h * 32 + ct * 16 + la;
                    float v = pj[rt][ct][r] + (ct ? pb1 : pb0);
                    outf[sr * 256 + col] = x_seq[sr * 256 + col] + (ct ? g1 : g0) * v;
                }
            }
        }
    }
}

// ---------------- fused MLP (round-10 best: v1 + hb stride 268 + setprio) --
__global__ __launch_bounds__(256, 2) void mlp_fused(float* __restrict__ outf,
                                                    const __hip_bfloat16* __restrict__ fc1w,
                                                    const float* __restrict__ fc1_b,
                                                    const __hip_bfloat16* __restrict__ fc2w,
                                                    const float* __restrict__ fc2_b,
                                                    const float* __restrict__ ada) {
    __shared__ u16 xa[64 * 264];
    __shared__ u16 hb[64 * 268];

    int tid = threadIdx.x;
    int lane = tid & 63;
    int w = tid >> 6;
    int la = lane & 15, lb = lane >> 4;
    long mrow = (long)blockIdx.x * 64;
    int nb = (int)(mrow >> 12);

    const u16* F1 = (const u16*)fc1w;   // [1024][256]
    const u16* F2 = (const u16*)fc2w;   // [256][1024]

    const float* sh = &ada[nb * 1536 + 768];
    const float* scp = &ada[nb * 1536 + 1024];
#pragma unroll
    for (int i = 0; i < 16; i++) {
        int row = i * 4 + w;
        const float4 v = *(const float4*)&outf[(mrow + row) * 256 + lane * 4];
        float s = v.x + v.y + v.z + v.w;
        float s2 = v.x * v.x + v.y * v.y + v.z * v.z + v.w * v.w;
#pragma unroll
        for (int o = 32; o > 0; o >>= 1) {
            s += __shfl_xor(s, o, 64);
            s2 += __shfl_xor(s2, o, 64);
        }
        float mu = s * (1.0f / 256.0f);
        float var = s2 * (1.0f / 256.0f) - mu * mu;
        float rstd = rsqrtf(var + 1e-6f);
        float vv[4] = {v.x, v.y, v.z, v.w};
#pragma unroll
        for (int e = 0; e < 4; e++) {
            int col = lane * 4 + e;
            float val = (vv[e] - mu) * rstd;
            val = val * (1.0f + scp[col]) + sh[col];
            xa[row * 264 + col] = f2bf(val);
        }
    }
    __syncthreads();

    f32x4 acc2[4][4] = {};

#pragma unroll 1
    for (int c = 0; c < 4; c++) {
        f32x4 acc1[4][4] = {};
        const u16* B1 = F1 + (long)(c * 256 + w * 64) * 256;
        s16x8 bc[8];
#pragma unroll
        for (int ct = 0; ct < 4; ct++)
#pragma unroll
            for (int kk = 0; kk < 2; kk++)
                bc[ct * 2 + kk] = *(const s16x8*)&B1[(ct * 16 + la) * 256 + kk * 32 + lb * 8];
#pragma unroll
        for (int k0 = 0; k0 < 4; k0++) {
            s16x8 bn[8];
            if (k0 < 3) {
#pragma unroll
                for (int ct = 0; ct < 4; ct++)
#pragma unroll
                    for (int kk = 0; kk < 2; kk++)
                        bn[ct * 2 + kk] = *(const s16x8*)&B1[(ct * 16 + la) * 256 +
                                                             (k0 + 1) * 64 + kk * 32 + lb * 8];
            }
            s16x8 a[4][2];
#pragma unroll
            for (int rt = 0; rt < 4; rt++)
#pragma unroll
                for (int kk = 0; kk < 2; kk++)
                    a[rt][kk] = *(const s16x8*)&xa[(rt * 16 + la) * 264 +
                                                   k0 * 64 + kk * 32 + lb * 8];
            __builtin_amdgcn_s_setprio(1);
#pragma unroll
            for (int kk = 0; kk < 2; kk++)
#pragma unroll
                for (int rt = 0; rt < 4; rt++)
#pragma unroll
                    for (int ct = 0; ct < 4; ct++)
                        acc1[rt][ct] = __builtin_amdgcn_mfma_f32_16x16x32_bf16(
                            a[rt][kk], bc[ct * 2 + kk], acc1[rt][ct], 0, 0, 0);
            __builtin_amdgcn_s_setprio(0);
            if (k0 < 3) {
#pragma unroll
                for (int q = 0; q < 8; q++) bc[q] = bn[q];
            }
        }
#pragma unroll
        for (int ct = 0; ct < 4; ct++) {
            float b1v = fc1_b[c * 256 + w * 64 + ct * 16 + la];
#pragma unroll
            for (int rt = 0; rt < 4; rt++) {
#pragma unroll
                for (int r = 0; r < 4; r++) {
                    float v = acc1[rt][ct][r] + b1v;
                    float u2 = 1.5957691216057308f * (v + 0.044715f * v * v * v);
                    hb[(rt * 16 + lb * 4 + r) * 268 + w * 64 + ct * 16 + la] =
                        f2bf(v / (1.0f + __expf(-u2)));
                }
            }
        }
        __syncthreads();

        const u16* B2 = F2 + (long)(w * 64) * 1024 + c * 256;
        s16x8 bc2[8];
#pragma unroll
        for (int ct = 0; ct < 4; ct++)
#pragma unroll
            for (int kk = 0; kk < 2; kk++)
                bc2[ct * 2 + kk] = *(const s16x8*)&B2[(ct * 16 + la) * 1024 + kk * 32 + lb * 8];
#pragma unroll
        for (int k0 = 0; k0 < 4; k0++) {
            s16x8 bn2[8];
            if (k0 < 3) {
#pragma unroll
                for (int ct = 0; ct < 4; ct++)
#pragma unroll
                    for (int kk = 0; kk < 2; kk++)
                        bn2[ct * 2 + kk] = *(const s16x8*)&B2[(ct * 16 + la) * 1024 +
                                                              (k0 + 1) * 64 + kk * 32 + lb * 8];
            }
            s16x8 a[4][2];
#pragma unroll
            for (int rt = 0; rt < 4; rt++)
#pragma unroll
                for (int kk = 0; kk < 2; kk++)
                    a[rt][kk] = *(const s16x8*)&hb[(rt * 16 + la) * 268 +
                                                   k0 * 64 + kk * 32 + lb * 8];
            __builtin_amdgcn_s_setprio(1);
#pragma unroll
            for (int kk = 0; kk < 2; kk++)
#pragma unroll
                for (int rt = 0; rt < 4; rt++)
#pragma unroll
                    for (int ct = 0; ct < 4; ct++)
                        acc2[rt][ct] = __builtin_amdgcn_mfma_f32_16x16x32_bf16(
                            a[rt][kk], bc2[ct * 2 + kk], acc2[rt][ct], 0, 0, 0);
            __builtin_amdgcn_s_setprio(0);
            if (k0 < 3) {
#pragma unroll
                for (int q = 0; q < 8; q++) bc2[q] = bn2[q];
            }
        }
        __syncthreads();
    }

#pragma unroll
    for (int ct = 0; ct < 4; ct++) {
        int col = w * 64 + ct * 16 + la;
        float g = ada[nb * 1536 + 1280 + col];
        float b2v = fc2_b[col];
#pragma unroll
        for (int rt = 0; rt < 4; rt++) {
#pragma unroll
            for (int r = 0; r < 4; r++) {
                long row = mrow + rt * 16 + lb * 4 + r;
                long oidx = row * 256 + col;
                outf[oidx] = outf[oidx] + g * (acc2[rt][ct][r] + b2v);
            }
        }
    }
}

// ---------------------------------------------------------------------------
extern "C" void kernel_launch(void* const* d_in, const int* in_sizes, int n_in,
                              void* d_out, int out_size, void* d_ws, size_t ws_size,
                              hipStream_t stream) {
    const float* x_seq  = (const float*)d_in[0];
    const float* c      = (const float*)d_in[1];
    const float* qkv_w  = (const float*)d_in[2];
    const float* qkv_b  = (const float*)d_in[3];
    const float* proj_w = (const float*)d_in[4];
    const float* proj_b = (const float*)d_in[5];
    const float* rpb    = (const float*)d_in[6];
    const float* ada_w  = (const float*)d_in[7];
    const float* ada_b  = (const float*)d_in[8];
    const float* fc1_w  = (const float*)d_in[9];
    const float* fc1_b  = (const float*)d_in[10];
    const float* fc2_w  = (const float*)d_in[11];
    const float* fc2_b  = (const float*)d_in[12];

    char* ws = (char*)d_ws;
    float* ada             = (float*)ws;                       // 96 KB
    __hip_bfloat16* qkv_wt = (__hip_bfloat16*)(ws + 131072);   // 768x256 bf16
    __hip_bfloat16* proj_wt= (__hip_bfloat16*)(ws + 524288);   // 256x256
    __hip_bfloat16* fc1_wt = (__hip_bfloat16*)(ws + 655360);   // 1024x256
    __hip_bfloat16* fc2_wt = (__hip_bfloat16*)(ws + 1179648);  // 256x1024
    float* outf = (float*)d_out;

    wconv_t<<<(256 * 768 + 255) / 256, 256, 0, stream>>>(qkv_w, qkv_wt, 256, 768);
    wconv_t<<<(256 * 256 + 255) / 256, 256, 0, stream>>>(proj_w, proj_wt, 256, 256);
    wconv_t<<<(256 * 1024 + 255) / 256, 256, 0, stream>>>(fc1_w, fc1_wt, 256, 1024);
    wconv_t<<<(1024 * 256 + 255) / 256, 256, 0, stream>>>(fc2_w, fc2_wt, 1024, 256);

    ada_kernel<<<6, 256, 0, stream>>>(c, ada_w, ada_b, ada);

    // fused LN1 + qkv + window attention + proj + residual -> d_out (f32)
    attn_mega<<<1024, 512, 0, stream>>>(x_seq, qkv_wt, qkv_b, proj_wt, proj_b,
                                        rpb, ada, outf);

    // fused MLP: LN+mod -> fc1 -> gelu -> fc2 -> out += g_mlp*h  (RMW d_out)
    mlp_fused<<<TTOT / 64, 256, 0, stream>>>(outf, fc1_wt, fc1_b, fc2_wt, fc2_b, ada);
}